// Round 15
// baseline (208.041 us; speedup 1.0000x reference)
//
#include <hip/hip_runtime.h>
#include <hip/hip_bf16.h>
#include <cstdint>

#define SEQ   720
#define PRED  720
#define CH    862
#define NB    64
#define NIN   360   // IN_LEN
#define KP    384   // padded K (12 * 32)
#define CP    896   // padded channels (7 * 128)
#define PP    768   // padded pred (6 * 128)
#define BK    32

typedef __attribute__((ext_vector_type(8))) short s16x8;
typedef __attribute__((ext_vector_type(4))) float f32x4;
typedef __attribute__((ext_vector_type(2))) float f32x2;
typedef unsigned int u32;
typedef unsigned short u16;

__device__ __forceinline__ u16 to_bf16u(float f){
  __hip_bfloat16 h = __float2bfloat16(f);
  return *reinterpret_cast<u16*>(&h);
}
__device__ __forceinline__ float from_bf16u(u16 u){
  u32 w = ((u32)u) << 16;
  return *reinterpret_cast<float*>(&w);
}

// ---------------- Fused prep0: Dt_bf (DCT^T bf16) | Wlo_bf cast | Srow/Slo (R13-verified) ----------------
__global__ __launch_bounds__(256) void k_prep0(const float* __restrict__ Wlo,
                                               u16* __restrict__ Dt, u16* __restrict__ Wbf,
                                               float* __restrict__ Srow, float* __restrict__ Slo){
  int bid = blockIdx.x, t = threadIdx.x;
  if (bid < 576){
    int idx = bid*256 + t;
    int m = idx / 384, n = idx % 384;
    u16 v = 0;
    if (m < NIN && n < NIN){
      int r = ((2*m+1)*n) % (4*NIN);
      float ang = (float)r * (float)(3.14159265358979323846 / 720.0);
      float x = cosf(ang) * 0.07453559924999299f;
      if (n == 0) x *= 0.7071067811865476f;
      v = to_bf16u(x);
    }
    Dt[idx] = v;
  } else if (bid < 1728){
    int idx = (bid - 576)*256 + t;
    int p = idx / 384, n = idx % 384;
    u16 v = 0;
    if (p < PRED && n < NIN) v = to_bf16u(Wlo[(size_t)p*NIN + n]);
    Wbf[idx] = v;
  } else {
    int w = t >> 6, l = t & 63;
    int p = (bid - 1728)*4 + w;
    if (p < PRED){
      const float* row = Wlo + (size_t)p*NIN;
      float s = 0.f;
      for (int i = l; i < NIN; i += 64) s += row[i];
      #pragma unroll
      for (int off = 32; off > 0; off >>= 1) s += __shfl_down(s, off);
      if (l == 0){
        Slo[p]  = s;
        Srow[p] = row[0] * 0.05270462766947299f;   // 1/sqrt(360), exact row-sum of M
      }
    }
  }
}

#define GLOAD_LDS16(gp, lp_) __builtin_amdgcn_global_load_lds( \
    (const __attribute__((address_space(1))) u32*)(gp), \
    (__attribute__((address_space(3))) u32*)(lp_), 16, 0, 0)

// ---------------- k_mgemm: Mbf = bf16( Wlo_bf x Dt_bf^T / 360 ) (R13-verified) ----------------
__global__ __launch_bounds__(256, 4) void k_mgemm(const u16* __restrict__ Wbf, const u16* __restrict__ Dt,
                                                  u16* __restrict__ Mbf){
  int bid = blockIdx.x;
  int pt = bid % 6;
  int mt = bid / 6;

  int t  = threadIdx.x;
  int w  = t >> 6, l = t & 63;
  int wr = w >> 1, wc = w & 1;

  __shared__ __align__(16) char smem[32768];
  u16 (*As)[128*BK] = reinterpret_cast<u16(*)[128*BK]>(smem);
  u16 (*Bs)[128*BK] = reinterpret_cast<u16(*)[128*BK]>(smem + 16384);
  float (*wb2)[132] = reinterpret_cast<float(*)[132]>(smem);

  f32x4 acc[4][4] = {};

  const u16* Abase = Wbf + (size_t)pt*128*KP;
  const u16* Bbase = Dt + (size_t)mt*128*KP;
  int srow = t >> 2;
  int squad = t & 3;
  int row16 = l & 15, kb = l >> 4;
  int sperm = (srow >> 1) & 3;
  int rperm = (row16 >> 1) & 3;

#define STAGEM(bufi, k0) do { \
    GLOAD_LDS16(Abase + (size_t)(srow)*KP + (k0) + ((squad^sperm))*8,      &As[bufi][(srow)*BK + squad*8]); \
    GLOAD_LDS16(Abase + (size_t)(64 + srow)*KP + (k0) + ((squad^sperm))*8, &As[bufi][(64 + srow)*BK + squad*8]); \
    GLOAD_LDS16(Bbase + (size_t)(srow)*KP + (k0) + ((squad^sperm))*8,      &Bs[bufi][(srow)*BK + squad*8]); \
    GLOAD_LDS16(Bbase + (size_t)(64 + srow)*KP + (k0) + ((squad^sperm))*8, &Bs[bufi][(64 + srow)*BK + squad*8]); \
  } while(0)

  STAGEM(0, 0);
  for (int ks = 0; ks < 12; ks++){
    int cur = ks & 1;
    if (ks < 11){
      STAGEM(cur ^ 1, (ks + 1) * BK);
      asm volatile("s_waitcnt vmcnt(4)" ::: "memory");
    } else {
      asm volatile("s_waitcnt vmcnt(0)" ::: "memory");
    }
    __builtin_amdgcn_s_barrier();
    const u16* aB = &As[cur][(wr*64 + row16)*BK + (kb^rperm)*8];
    const u16* bB = &Bs[cur][(wc*64 + row16)*BK + (kb^rperm)*8];
    s16x8 bfr[4];
    #pragma unroll
    for (int ni = 0; ni < 4; ni++)
      bfr[ni] = *reinterpret_cast<const s16x8*>(bB + ni*16*BK);
    #pragma unroll
    for (int mi = 0; mi < 4; mi++){
      s16x8 af = *reinterpret_cast<const s16x8*>(aB + mi*16*BK);
      #pragma unroll
      for (int ni = 0; ni < 4; ni++)
        acc[mi][ni] = __builtin_amdgcn_mfma_f32_16x16x32_bf16(af, bfr[ni], acc[mi][ni], 0, 0, 0);
    }
    __builtin_amdgcn_s_barrier();
  }
  __syncthreads();

  const float inv360 = 1.0f/360.0f;
  #pragma unroll 1
  for (int mi = 0; mi < 4; mi++){
    #pragma unroll
    for (int ni = 0; ni < 4; ni++)
      #pragma unroll
      for (int r = 0; r < 4; r++)
        wb2[wr*16 + kb*4 + r][wc*64 + ni*16 + row16] = acc[mi][ni][r];
    __syncthreads();
    #pragma unroll
    for (int it = 0; it < 2; it++){
      int wi = it*256 + t;
      int rl = wi >> 4, seg = wi & 15;
      int p = pt*128 + (rl>>4)*64 + mi*16 + (rl & 15);
      f32x4 g0 = *reinterpret_cast<const f32x4*>(&wb2[rl][seg*8]);
      f32x4 g1 = *reinterpret_cast<const f32x4*>(&wb2[rl][seg*8 + 4]);
      uint4 pk;
      pk.x = (u32)to_bf16u(g0.x*inv360) | ((u32)to_bf16u(g0.y*inv360) << 16);
      pk.y = (u32)to_bf16u(g0.z*inv360) | ((u32)to_bf16u(g0.w*inv360) << 16);
      pk.z = (u32)to_bf16u(g1.x*inv360) | ((u32)to_bf16u(g1.y*inv360) << 16);
      pk.w = (u32)to_bf16u(g1.z*inv360) | ((u32)to_bf16u(g1.w*inv360) << 16);
      *reinterpret_cast<uint4*>(&Mbf[(size_t)p*KP + mt*128 + seg*8]) = pk;
    }
    __syncthreads();
  }
}

// ---------------- Kernel C: pair sums -> bf16 A-matrix, two 192-row halves (R10-verified) ----------------
__global__ __launch_bounds__(256) void k_pre(const float* __restrict__ x, u16* __restrict__ pairB,
                                             float* __restrict__ meanw){
  int b  = blockIdx.y;
  int c0 = blockIdx.x * 64;
  int t  = threadIdx.x;
  int c16  = t & 15;
  int mrow = t >> 4;
  int w    = t >> 6;
  __shared__ u16  pl[192][66];
  __shared__ float red[4][64];
  const float rs2 = 0.7071067811865476f;
  int cb = c0 + c16*4;
  bool full = (cb + 3 < CH);
  const float* xb = x + (size_t)b*SEQ*CH + cb;
  float s0=0.f, s1=0.f, s2=0.f, s3=0.f;
  int rowc = t >> 2;
  int mq0  = t & 3;
  size_t rbase = ((size_t)b*CP + c0 + rowc) * KP;

  #pragma unroll 1
  for (int h = 0; h < 2; h++){
    #pragma unroll 1
    for (int ml = mrow; ml < 192; ml += 16){
      int m = h*192 + ml;
      float p0=0.f, p1=0.f, p2=0.f, p3=0.f;
      if (m < NIN){
        const float* r0 = xb + (size_t)(2*m)*CH;
        float a0,a1,a2,a3, e0,e1,e2,e3;
        if (full){
          f32x4 va = *reinterpret_cast<const f32x4*>(r0);
          f32x2 vb = *reinterpret_cast<const f32x2*>(r0 + CH);
          f32x2 vc = *reinterpret_cast<const f32x2*>(r0 + CH + 2);
          a0=va.x; a1=va.y; a2=va.z; a3=va.w;
          e0=vb.x; e1=vb.y; e2=vc.x; e3=vc.y;
        } else {
          a0 = (cb+0<CH)? r0[0]:0.f; a1 = (cb+1<CH)? r0[1]:0.f;
          a2 = (cb+2<CH)? r0[2]:0.f; a3 = (cb+3<CH)? r0[3]:0.f;
          e0 = (cb+0<CH)? r0[CH+0]:0.f; e1 = (cb+1<CH)? r0[CH+1]:0.f;
          e2 = (cb+2<CH)? r0[CH+2]:0.f; e3 = (cb+3<CH)? r0[CH+3]:0.f;
        }
        p0=a0+e0; p1=a1+e1; p2=a2+e2; p3=a3+e3;
        s0+=p0; s1+=p1; s2+=p2; s3+=p3;
      }
      u32 lo = (u32)to_bf16u(p0*rs2) | ((u32)to_bf16u(p1*rs2) << 16);
      u32 hi = (u32)to_bf16u(p2*rs2) | ((u32)to_bf16u(p3*rs2) << 16);
      *reinterpret_cast<u32*>(&pl[ml][c16*4 + 0]) = lo;
      *reinterpret_cast<u32*>(&pl[ml][c16*4 + 2]) = hi;
    }
    __syncthreads();
    #pragma unroll
    for (int i = 0; i < 6; i++){
      int mg = mq0 + 4*i;
      u16 vals[8];
      #pragma unroll
      for (int j = 0; j < 8; j++) vals[j] = pl[mg*8 + j][rowc];
      uint4 pk;
      pk.x = (u32)vals[0] | ((u32)vals[1] << 16);
      pk.y = (u32)vals[2] | ((u32)vals[3] << 16);
      pk.z = (u32)vals[4] | ((u32)vals[5] << 16);
      pk.w = (u32)vals[6] | ((u32)vals[7] << 16);
      *reinterpret_cast<uint4*>(pairB + rbase + h*192 + (size_t)mg*8) = pk;
    }
    __syncthreads();
  }

  s0 += __shfl_down(s0, 32); s1 += __shfl_down(s1, 32);
  s2 += __shfl_down(s2, 32); s3 += __shfl_down(s3, 32);
  s0 += __shfl_down(s0, 16); s1 += __shfl_down(s1, 16);
  s2 += __shfl_down(s2, 16); s3 += __shfl_down(s3, 16);
  if ((t & 63) < 16){
    f32x4 rv; rv.x=s0; rv.y=s1; rv.z=s2; rv.w=s3;
    *reinterpret_cast<f32x4*>(&red[w][c16*4]) = rv;
  }
  __syncthreads();
  if (t < 64){
    float mean = (red[0][t] + red[1][t] + red[2][t] + red[3][t]) * (1.0f/SEQ);
    meanw[(size_t)b*CP + c0 + t] = mean;
  }
}

// ---------------- Kernel D: GEMM -> bf16 G, block-contiguous 32 KB chunks (no affine) ----------------
// G layout: [b][pt(6)][ct(7)][128 p][128 c] bf16; each block writes ONE contiguous 32 KB chunk.
__global__ __launch_bounds__(256, 4) void k_gemm(const u16* __restrict__ Apack, const u16* __restrict__ Mbf,
                                                 u16* __restrict__ G){
  // XCD-aware bijective swizzle: 2688 = 8 * 336.
  int bid = blockIdx.x;
  int idx = (bid & 7) * 336 + (bid >> 3);
  int pt  = idx % 6;
  int rem = idx / 6;
  int ct  = rem % 7;
  int b   = rem / 7;

  int t  = threadIdx.x;
  int w  = t >> 6, l = t & 63;
  int wr = w >> 1, wc = w & 1;

  __shared__ __align__(16) char smem[32768];
  u16 (*As)[128*BK] = reinterpret_cast<u16(*)[128*BK]>(smem);
  u16 (*Bs)[128*BK] = reinterpret_cast<u16(*)[128*BK]>(smem + 16384);
  float (*wbuf)[16][132] = reinterpret_cast<float(*)[16][132]>(smem);

  f32x4 acc[4][4] = {};

  const u16* Abase = Apack + ((size_t)b*CP + (size_t)ct*128) * KP;
  const u16* Bbase = Mbf + (size_t)pt*128*KP;
  int srow = t >> 2;
  int squad = t & 3;
  int row16 = l & 15, kb = l >> 4;
  int sperm = (srow >> 1) & 3;
  int rperm = (row16 >> 1) & 3;

#define STAGE(bufi, k0) do { \
    GLOAD_LDS16(Abase + (size_t)(srow)*KP + (k0) + ((squad^sperm))*8,      &As[bufi][(srow)*BK + squad*8]); \
    GLOAD_LDS16(Abase + (size_t)(64 + srow)*KP + (k0) + ((squad^sperm))*8, &As[bufi][(64 + srow)*BK + squad*8]); \
    GLOAD_LDS16(Bbase + (size_t)(srow)*KP + (k0) + ((squad^sperm))*8,      &Bs[bufi][(srow)*BK + squad*8]); \
    GLOAD_LDS16(Bbase + (size_t)(64 + srow)*KP + (k0) + ((squad^sperm))*8, &Bs[bufi][(64 + srow)*BK + squad*8]); \
  } while(0)

  STAGE(0, 0);
  for (int ks = 0; ks < 12; ks++){
    int cur = ks & 1;
    if (ks < 11){
      STAGE(cur ^ 1, (ks + 1) * BK);
      asm volatile("s_waitcnt vmcnt(4)" ::: "memory");
    } else {
      asm volatile("s_waitcnt vmcnt(0)" ::: "memory");
    }
    __builtin_amdgcn_s_barrier();
    const u16* aB = &As[cur][(wr*64 + row16)*BK + (kb^rperm)*8];
    const u16* bB = &Bs[cur][(wc*64 + row16)*BK + (kb^rperm)*8];
    s16x8 bfr[4];
    #pragma unroll
    for (int ni = 0; ni < 4; ni++)
      bfr[ni] = *reinterpret_cast<const s16x8*>(bB + ni*16*BK);
    __builtin_amdgcn_s_setprio(1);
    #pragma unroll
    for (int mi = 0; mi < 4; mi++){
      s16x8 af = *reinterpret_cast<const s16x8*>(aB + mi*16*BK);
      #pragma unroll
      for (int ni = 0; ni < 4; ni++)
        acc[mi][ni] = __builtin_amdgcn_mfma_f32_16x16x32_bf16(af, bfr[ni], acc[mi][ni], 0, 0, 0);
    }
    __builtin_amdgcn_s_setprio(0);
    __builtin_amdgcn_s_barrier();
  }
  __syncthreads();   // full fence before wbuf aliases As/Bs

  // ---- epilogue: wbuf transpose -> bf16 pack -> contiguous 32 KB G chunk ----
  size_t gbase = (((size_t)b*6 + pt)*7 + ct) * (size_t)(128*128);
  int c32 = t & 31;
  int prow = t >> 5;   // 0..7

  #pragma unroll
  for (int ni = 0; ni < 4; ni++){
    #pragma unroll
    for (int mi = 0; mi < 4; mi++)
      #pragma unroll
      for (int r = 0; r < 4; r++)
        wbuf[wc][row16][wr*64 + mi*16 + kb*4 + r] = acc[mi][ni][r];
    __syncthreads();
    #pragma unroll
    for (int k = 0; k < 4; k++){
      int wcp   = k >> 1;
      int p_loc = (k & 1)*8 + prow;
      int prow_g = wcp*64 + ni*16 + p_loc;          // 0..127 within chunk
      f32x4 g = *reinterpret_cast<const f32x4*>(&wbuf[wcp][p_loc][c32*4]);
      uint2 pk;
      pk.x = (u32)to_bf16u(g.x) | ((u32)to_bf16u(g.y) << 16);
      pk.y = (u32)to_bf16u(g.z) | ((u32)to_bf16u(g.w) << 16);
      *reinterpret_cast<uint2*>(&G[gbase + (size_t)prow_g*128 + c32*4]) = pk;
    }
    __syncthreads();
  }
}

// ---------------- Kernel E: streaming epilogue — affine + fully sequential out writes ----------------
// Block = (b, pt, half): 64 contiguous p-rows; per instruction a wave writes 1 KB contiguous.
__global__ __launch_bounds__(256) void k_out(const u16* __restrict__ G,
                                             const float* __restrict__ Srow, const float* __restrict__ Slo,
                                             const float* __restrict__ meanw,
                                             const float* __restrict__ w1, const float* __restrict__ b1,
                                             const float* __restrict__ w2, const float* __restrict__ b2,
                                             const float* __restrict__ blo,
                                             float* __restrict__ out){
  int bid = blockIdx.x;             // 768 = 64 * 6 * 2
  int half = bid & 1;
  int pt   = (bid >> 1) % 6;
  int b    = bid / 12;
  int t = threadIdx.x;
  int w = t >> 6, l = t & 63;

  const u16* gb = G + (((size_t)b*6 + pt)*7) * (size_t)(128*128);
  size_t outb = (size_t)b*PRED*CH;
  const float rt2 = 1.4142135623730951f;

  #pragma unroll 1
  for (int i = 0; i < 4; i++){
    int c = l*4 + i*256;            // 0..1020
    if (c >= 896) continue;         // lanes 24..63 idle on i==3 (uniform per lane across rows)
    int ctc = c >> 7, cl = c & 127;
    const u16* gchunk = gb + (size_t)ctc*(128*128) + cl;
    // hoisted per-c constants
    float sc4[4], of4[4], mv4[4];
    bool cfull = (c + 3 < CH);
    #pragma unroll
    for (int j = 0; j < 4; j++){
      int cc = (c + j < CH) ? (c + j) : (CH - 1);
      float w1v = w1[cc], w2v = w2[cc];
      sc4[j] = 1.f + w1v*w2v;
      of4[j] = w1v*b2[cc] + b1[cc];
      mv4[j] = meanw[(size_t)b*CP + c + j];    // meanw padded to CP
    }
    float cn4[4], bc4[4];
    #pragma unroll
    for (int j = 0; j < 4; j++){
      cn4[j] = mv4[j];
      bc4[j] = rt2 * sc4[j] * mv4[j];
    }
    #pragma unroll 1
    for (int rr = 0; rr < 16; rr++){
      int p_loc = half*64 + w*16 + rr;     // 0..127
      int p = pt*128 + p_loc;
      if (p >= PRED) continue;
      uint2 gp = *reinterpret_cast<const uint2*>(gchunk + (size_t)p_loc*128);
      float g0 = from_bf16u((u16)(gp.x & 0xffff)), g1 = from_bf16u((u16)(gp.x >> 16));
      float g2 = from_bf16u((u16)(gp.y & 0xffff)), g3 = from_bf16u((u16)(gp.y >> 16));
      float sp = Srow[p], sl = Slo[p], bl = blo[p];
      float base0 = -0.f;
      f32x4 ov;
      ov.x = sc4[0]*g0 + (cn4[0] - bc4[0]*sp + of4[0]*sl + bl);
      ov.y = sc4[1]*g1 + (cn4[1] - bc4[1]*sp + of4[1]*sl + bl);
      ov.z = sc4[2]*g2 + (cn4[2] - bc4[2]*sp + of4[2]*sl + bl);
      ov.w = sc4[3]*g3 + (cn4[3] - bc4[3]*sp + of4[3]*sl + bl);
      (void)base0;
      float* op = &out[outb + (size_t)p*CH + c];
      if (cfull){
        *reinterpret_cast<f32x4*>(op) = ov;
      } else {
        #pragma unroll
        for (int j = 0; j < 4; j++)
          if (c + j < CH) op[j] = ov[j];
      }
    }
  }
}

extern "C" void kernel_launch(void* const* d_in, const int* in_sizes, int n_in,
                              void* d_out, int out_size, void* d_ws, size_t ws_size,
                              hipStream_t stream)
{
  const float* x   = (const float*)d_in[0];
  const float* w1  = (const float*)d_in[1];
  const float* b1  = (const float*)d_in[2];
  const float* w2  = (const float*)d_in[3];
  const float* b2  = (const float*)d_in[4];
  const float* Wlo = (const float*)d_in[5];
  const float* blo = (const float*)d_in[6];
  float* out = (float*)d_out;

  char* ws = (char*)d_ws;
  u16*   Dt    = (u16*)(ws);                       // 294912 B
  u16*   Wbf   = (u16*)(ws + 294912);              // 589824 B
  u16*   Mbf   = (u16*)(ws + 884736);              // 589824 B
  float* Srow  = (float*)(ws + 1474560);           // 3072 B
  float* Slo   = (float*)(ws + 1477632);           // 3072 B
  u16*   pairB = (u16*)(ws + 1480704);             // 44040192 B
  float* meanw = (float*)(ws + 45520896);          // 229376 B
  u16*   G     = (u16*)(ws + 45750272);            // 88080384 B

  k_prep0<<<dim3(1908), dim3(256), 0, stream>>>(Wlo, Dt, Wbf, Srow, Slo);
  k_mgemm<<<dim3(18), dim3(256), 0, stream>>>(Wbf, Dt, Mbf);
  k_pre<<<dim3(CP/64, NB), dim3(256), 0, stream>>>(x, pairB, meanw);
  k_gemm<<<dim3(6*7*NB), dim3(256), 0, stream>>>(pairB, Mbf, G);
  k_out<<<dim3(NB*6*2), dim3(256), 0, stream>>>(G, Srow, Slo, meanw, w1, b1, w2, b2, blo, out);
}

// Round 16
// 206.887 us; speedup vs baseline: 1.0056x; 1.0056x over previous
//
#include <hip/hip_runtime.h>
#include <hip/hip_bf16.h>
#include <cstdint>

#define SEQ   720
#define PRED  720
#define CH    862
#define NB    64
#define NIN   360   // IN_LEN
#define KP    384   // padded K (12 * 32)
#define CP    896   // padded channels (7 * 128)
#define PP    768   // padded pred (6 * 128)
#define BK    32

typedef __attribute__((ext_vector_type(8))) short s16x8;
typedef __attribute__((ext_vector_type(4))) float f32x4;
typedef __attribute__((ext_vector_type(2))) float f32x2;
typedef unsigned int u32;
typedef unsigned short u16;

__device__ __forceinline__ u16 to_bf16u(float f){
  __hip_bfloat16 h = __float2bfloat16(f);
  return *reinterpret_cast<u16*>(&h);
}

// ---------------- Kernel A: DCT-II ortho matrix D[n][m], n,m in [0,360) ----------------
__global__ __launch_bounds__(256) void k_dct(float* __restrict__ Dm){
  int idx = blockIdx.x*256 + threadIdx.x;
  if (idx >= NIN*NIN) return;
  int n = idx / NIN, m = idx % NIN;
  int r = ((2*m+1)*n) % (4*NIN);
  float ang = (float)r * (float)(3.14159265358979323846 / 720.0);
  float v = cosf(ang) * 0.07453559924999299f;   // sqrt(2/360)
  if (n == 0) v *= 0.7071067811865476f;
  Dm[idx] = v;
}

// ---------------- Merged prep: blocks [0,896) = pair-sum/mean (R10 k_pre, 26.4 KB LDS);
//                  blocks [896,1664) = M-matrix row (R7-verified 256-thread mmat, 1.5 KB) ----------------
__global__ __launch_bounds__(256) void k_prep(const float* __restrict__ x, const float* __restrict__ Wlo,
                                              const float* __restrict__ Dm,
                                              u16* __restrict__ pairB, float* __restrict__ meanw,
                                              u16* __restrict__ Mbf, float* __restrict__ Srow,
                                              float* __restrict__ Slo){
  __shared__ __align__(16) char smem[26368];
  int bid = blockIdx.x;
  int t   = threadIdx.x;

  if (bid < NB*14){
    // ================= pre path (R10-verified: two 192-row halves) =================
    u16 (*pl)[66]    = reinterpret_cast<u16(*)[66]>(smem);             // [192][66] = 25344 B
    float (*red)[64] = reinterpret_cast<float(*)[64]>(smem + 25344);   // [4][64]   = 1024 B
    int ct = bid % 14;
    int b  = bid / 14;
    int c0 = ct * 64;
    int c16  = t & 15;
    int mrow = t >> 4;
    int w    = t >> 6;
    const float rs2 = 0.7071067811865476f;
    int cb = c0 + c16*4;
    bool full = (cb + 3 < CH);
    const float* xb = x + (size_t)b*SEQ*CH + cb;
    float s0=0.f, s1=0.f, s2=0.f, s3=0.f;
    int rowc = t >> 2;
    int mq0  = t & 3;
    size_t rbase = ((size_t)b*CP + c0 + rowc) * KP;

    #pragma unroll 1
    for (int h = 0; h < 2; h++){
      #pragma unroll 1
      for (int ml = mrow; ml < 192; ml += 16){
        int m = h*192 + ml;
        float p0=0.f, p1=0.f, p2=0.f, p3=0.f;
        if (m < NIN){
          const float* r0 = xb + (size_t)(2*m)*CH;
          float a0,a1,a2,a3, e0,e1,e2,e3;
          if (full){
            f32x4 va = *reinterpret_cast<const f32x4*>(r0);
            f32x2 vb = *reinterpret_cast<const f32x2*>(r0 + CH);
            f32x2 vc = *reinterpret_cast<const f32x2*>(r0 + CH + 2);
            a0=va.x; a1=va.y; a2=va.z; a3=va.w;
            e0=vb.x; e1=vb.y; e2=vc.x; e3=vc.y;
          } else {
            a0 = (cb+0<CH)? r0[0]:0.f; a1 = (cb+1<CH)? r0[1]:0.f;
            a2 = (cb+2<CH)? r0[2]:0.f; a3 = (cb+3<CH)? r0[3]:0.f;
            e0 = (cb+0<CH)? r0[CH+0]:0.f; e1 = (cb+1<CH)? r0[CH+1]:0.f;
            e2 = (cb+2<CH)? r0[CH+2]:0.f; e3 = (cb+3<CH)? r0[CH+3]:0.f;
          }
          p0=a0+e0; p1=a1+e1; p2=a2+e2; p3=a3+e3;
          s0+=p0; s1+=p1; s2+=p2; s3+=p3;
        }
        u32 lo = (u32)to_bf16u(p0*rs2) | ((u32)to_bf16u(p1*rs2) << 16);
        u32 hi = (u32)to_bf16u(p2*rs2) | ((u32)to_bf16u(p3*rs2) << 16);
        *reinterpret_cast<u32*>(&pl[ml][c16*4 + 0]) = lo;
        *reinterpret_cast<u32*>(&pl[ml][c16*4 + 2]) = hi;
      }
      __syncthreads();
      #pragma unroll
      for (int i = 0; i < 6; i++){
        int mg = mq0 + 4*i;
        u16 vals[8];
        #pragma unroll
        for (int j = 0; j < 8; j++) vals[j] = pl[mg*8 + j][rowc];
        uint4 pk;
        pk.x = (u32)vals[0] | ((u32)vals[1] << 16);
        pk.y = (u32)vals[2] | ((u32)vals[3] << 16);
        pk.z = (u32)vals[4] | ((u32)vals[5] << 16);
        pk.w = (u32)vals[6] | ((u32)vals[7] << 16);
        *reinterpret_cast<uint4*>(pairB + rbase + h*192 + (size_t)mg*8) = pk;
      }
      __syncthreads();
    }

    s0 += __shfl_down(s0, 32); s1 += __shfl_down(s1, 32);
    s2 += __shfl_down(s2, 32); s3 += __shfl_down(s3, 32);
    s0 += __shfl_down(s0, 16); s1 += __shfl_down(s1, 16);
    s2 += __shfl_down(s2, 16); s3 += __shfl_down(s3, 16);
    if ((t & 63) < 16){
      f32x4 rv; rv.x=s0; rv.y=s1; rv.z=s2; rv.w=s3;
      *reinterpret_cast<f32x4*>(&red[w][c16*4]) = rv;
    }
    __syncthreads();
    if (t < 64){
      float mean = (red[0][t] + red[1][t] + red[2][t] + red[3][t]) * (1.0f/SEQ);
      meanw[(size_t)b*CP + c0 + t] = mean;
    }
  } else {
    // ================= mmat path (R7-verified, 256 threads, block = one p row) =================
    float* Wrow = reinterpret_cast<float*>(smem);          // [360]
    float* redM = Wrow + 360;                              // [4]
    float* redW = redM + 4;                                // [4]
    int p = bid - NB*14;
    if (p >= PRED){
      Mbf[(size_t)p*KP + t] = 0;
      if (t < KP-256) Mbf[(size_t)p*KP + 256 + t] = 0;
      if (t == 0){ Srow[p] = 0.f; Slo[p] = 0.f; }
      return;
    }
    Wrow[t] = Wlo[(size_t)p*NIN + t];
    if (t < NIN-256) Wrow[256 + t] = Wlo[(size_t)p*NIN + 256 + t];
    __syncthreads();
    int m0 = t, m1 = t + 256;
    bool has1 = (m1 < NIN);
    float a0 = 0.f, a1 = 0.f;
    const float* Dc = Dm;
    #pragma unroll 4
    for (int n = 0; n < NIN; n++){
      float wn = Wrow[n];
      a0 += wn * Dc[m0];
      if (has1) a1 += wn * Dc[m1];
      Dc += NIN;
    }
    a0 *= (1.0f/360.0f);
    a1 *= (1.0f/360.0f);
    Mbf[(size_t)p*KP + m0] = to_bf16u(a0);
    if (t < 128) Mbf[(size_t)p*KP + m1] = has1 ? to_bf16u(a1) : (u16)0;

    float mv = a0 + (has1 ? a1 : 0.f);
    float wv = Wrow[t] + ((t < NIN-256) ? Wrow[256 + t] : 0.f);
    #pragma unroll
    for (int off = 32; off > 0; off >>= 1){
      mv += __shfl_down(mv, off);
      wv += __shfl_down(wv, off);
    }
    int wid = t >> 6, lid = t & 63;
    if (lid == 0){ redM[wid] = mv; redW[wid] = wv; }
    __syncthreads();
    if (t == 0){
      float sm = 0.f, sw = 0.f;
      #pragma unroll
      for (int i = 0; i < 4; i++){ sm += redM[i]; sw += redW[i]; }
      Srow[p] = sm; Slo[p] = sw;
    }
  }
}

// ---------------- Kernel D: GEMM G = A * M^T (+ fused epilogue) — R10-verified (best measured) ----------------
#define GLOAD_LDS16(gp, lp_) __builtin_amdgcn_global_load_lds( \
    (const __attribute__((address_space(1))) u32*)(gp), \
    (__attribute__((address_space(3))) u32*)(lp_), 16, 0, 0)

__global__ __launch_bounds__(256, 4) void k_gemm(const u16* __restrict__ Apack, const u16* __restrict__ Mbf,
                                              const float* __restrict__ Srow, const float* __restrict__ Slo,
                                              const float* __restrict__ meanw,
                                              const float* __restrict__ w1, const float* __restrict__ b1,
                                              const float* __restrict__ w2, const float* __restrict__ b2,
                                              const float* __restrict__ blo,
                                              float* __restrict__ out){
  // XCD-aware bijective swizzle: 2688 = 8 * 336.
  int bid = blockIdx.x;
  int idx = (bid & 7) * 336 + (bid >> 3);
  int pt  = idx % 6;
  int rem = idx / 6;
  int ct  = rem % 7;
  int b   = rem / 7;

  int t  = threadIdx.x;
  int w  = t >> 6, l = t & 63;
  int wr = w >> 1, wc = w & 1;

  // 32 KB union: As[2]+Bs[2] during K-loop; wbuf (16.9 KB) during epilogue.
  __shared__ __align__(16) char smem[32768];
  u16 (*As)[128*BK] = reinterpret_cast<u16(*)[128*BK]>(smem);
  u16 (*Bs)[128*BK] = reinterpret_cast<u16(*)[128*BK]>(smem + 16384);
  float (*wbuf)[16][132] = reinterpret_cast<float(*)[16][132]>(smem);  // [wc][p16][c128+pad]

  f32x4 acc[4][4] = {};

  const u16* Abase = Apack + ((size_t)b*CP + (size_t)ct*128) * KP;
  const u16* Bbase = Mbf + (size_t)pt*128*KP;
  int srow = t >> 2;
  int squad = t & 3;
  int row16 = l & 15, kb = l >> 4;
  int sperm = (srow >> 1) & 3;        // write-side XOR swizzle (global src pre-swizzled)
  int rperm = (row16 >> 1) & 3;       // read-side XOR swizzle (same involution)

#define STAGE(bufi, k0) do { \
    GLOAD_LDS16(Abase + (size_t)(srow)*KP + (k0) + ((squad^sperm))*8,      &As[bufi][(srow)*BK + squad*8]); \
    GLOAD_LDS16(Abase + (size_t)(64 + srow)*KP + (k0) + ((squad^sperm))*8, &As[bufi][(64 + srow)*BK + squad*8]); \
    GLOAD_LDS16(Bbase + (size_t)(srow)*KP + (k0) + ((squad^sperm))*8,      &Bs[bufi][(srow)*BK + squad*8]); \
    GLOAD_LDS16(Bbase + (size_t)(64 + srow)*KP + (k0) + ((squad^sperm))*8, &Bs[bufi][(64 + srow)*BK + squad*8]); \
  } while(0)

  STAGE(0, 0);
  for (int ks = 0; ks < 12; ks++){
    int cur = ks & 1;
    if (ks < 11){
      STAGE(cur ^ 1, (ks + 1) * BK);
      asm volatile("s_waitcnt vmcnt(4)" ::: "memory");
    } else {
      asm volatile("s_waitcnt vmcnt(0)" ::: "memory");
    }
    __builtin_amdgcn_s_barrier();
    s16x8 af[4], bfr[4];
    #pragma unroll
    for (int mi = 0; mi < 4; mi++)
      af[mi] = *reinterpret_cast<const s16x8*>(&As[cur][(wr*64 + mi*16 + row16)*BK + (kb^rperm)*8]);
    #pragma unroll
    for (int ni = 0; ni < 4; ni++)
      bfr[ni] = *reinterpret_cast<const s16x8*>(&Bs[cur][(wc*64 + ni*16 + row16)*BK + (kb^rperm)*8]);
    __builtin_amdgcn_s_setprio(1);
    #pragma unroll
    for (int mi = 0; mi < 4; mi++)
      #pragma unroll
      for (int ni = 0; ni < 4; ni++)
        acc[mi][ni] = __builtin_amdgcn_mfma_f32_16x16x32_bf16(af[mi], bfr[ni], acc[mi][ni], 0, 0, 0);
    __builtin_amdgcn_s_setprio(0);
    __builtin_amdgcn_s_barrier();
  }
  __syncthreads();   // full fence before wbuf aliases As/Bs

  // ---- epilogue: cross-wave wbuf -> 512 B-segment stores ----
  int c32 = t & 31;
  int cb4 = ct*128 + c32*4;
  float sc4[4], of4[4], cn4[4], bc4[4];
  #pragma unroll
  for (int j = 0; j < 4; j++){
    int c = cb4 + j;
    bool v = (c < CH);
    float w1v = v ? w1[c] : 0.f, w2v = v ? w2[c] : 0.f;
    float b1v = v ? b1[c] : 0.f, b2v = v ? b2[c] : 0.f;
    float mv  = v ? meanw[(size_t)b*CP + c] : 0.f;
    sc4[j] = 1.f + w1v*w2v;
    of4[j] = w1v*b2v + b1v;
    cn4[j] = mv;
    bc4[j] = 1.4142135623730951f * sc4[j] * mv;
  }
  bool cfull = (cb4 + 3 < CH);
  size_t outb = (size_t)b*PRED*CH;
  int prow = t >> 5;   // 0..7

  #pragma unroll
  for (int ni = 0; ni < 4; ni++){
    #pragma unroll
    for (int mi = 0; mi < 4; mi++)
      #pragma unroll
      for (int r = 0; r < 4; r++)
        wbuf[wc][row16][wr*64 + mi*16 + kb*4 + r] = acc[mi][ni][r];
    __syncthreads();
    #pragma unroll
    for (int k = 0; k < 4; k++){
      int wcp   = k >> 1;
      int p_loc = (k & 1)*8 + prow;
      int p = pt*128 + wcp*64 + ni*16 + p_loc;
      if (p < PRED){
        f32x4 g = *reinterpret_cast<const f32x4*>(&wbuf[wcp][p_loc][c32*4]);
        float sp = Srow[p], sl = Slo[p], bl = blo[p];
        f32x4 ov;
        #pragma unroll
        for (int j = 0; j < 4; j++)
          ov[j] = sc4[j]*g[j] + (cn4[j] - bc4[j]*sp + of4[j]*sl + bl);
        float* op = &out[outb + (size_t)p*CH + cb4];
        if (cfull){
          *reinterpret_cast<f32x4*>(op) = ov;
        } else {
          #pragma unroll
          for (int j = 0; j < 4; j++)
            if (cb4 + j < CH) op[j] = ov[j];
        }
      }
    }
    __syncthreads();
  }
}

extern "C" void kernel_launch(void* const* d_in, const int* in_sizes, int n_in,
                              void* d_out, int out_size, void* d_ws, size_t ws_size,
                              hipStream_t stream)
{
  const float* x   = (const float*)d_in[0];
  const float* w1  = (const float*)d_in[1];
  const float* b1  = (const float*)d_in[2];
  const float* w2  = (const float*)d_in[3];
  const float* b2  = (const float*)d_in[4];
  const float* Wlo = (const float*)d_in[5];
  const float* blo = (const float*)d_in[6];
  float* out = (float*)d_out;

  char* ws = (char*)d_ws;
  float* Dm    = (float*)(ws);
  u16*   Mbf   = (u16*)(ws + 518400);
  float* Srow  = (float*)(ws + 518400 + 589824);
  float* Slo   = (float*)(ws + 518400 + 589824 + 3072);
  u16*   pairB = (u16*)(ws + 518400 + 589824 + 6144);
  float* meanw = (float*)(ws + 518400 + 589824 + 6144 + 44040192);

  k_dct<<<dim3((NIN*NIN + 255)/256), dim3(256), 0, stream>>>(Dm);
  k_prep<<<dim3(NB*14 + PP), dim3(256), 0, stream>>>(x, Wlo, Dm, pairB, meanw, Mbf, Srow, Slo);
  k_gemm<<<dim3(6*7*NB), dim3(256), 0, stream>>>(pairB, Mbf, Srow, Slo, meanw,
                                                 w1, b1, w2, b2, blo, out);
}

// Round 17
// 182.672 us; speedup vs baseline: 1.1389x; 1.1326x over previous
//
#include <hip/hip_runtime.h>
#include <hip/hip_bf16.h>
#include <cstdint>

#define SEQ   720
#define PRED  720
#define CH    862
#define NB    64
#define NIN   360   // IN_LEN
#define KP    384   // padded K (12 * 32)
#define CP    896   // padded channels (14 * 64)
#define PP    768   // padded pred (12 * 64)
#define BK    32

typedef __attribute__((ext_vector_type(8))) short s16x8;
typedef __attribute__((ext_vector_type(4))) float f32x4;
typedef __attribute__((ext_vector_type(2))) float f32x2;
typedef unsigned int u32;
typedef unsigned short u16;

__device__ __forceinline__ u16 to_bf16u(float f){
  __hip_bfloat16 h = __float2bfloat16(f);
  return *reinterpret_cast<u16*>(&h);
}

// ---------------- Kernel A: DCT-II ortho matrix D[n][m], n,m in [0,360) ----------------
__global__ __launch_bounds__(256) void k_dct(float* __restrict__ Dm){
  int idx = blockIdx.x*256 + threadIdx.x;
  if (idx >= NIN*NIN) return;
  int n = idx / NIN, m = idx % NIN;
  int r = ((2*m+1)*n) % (4*NIN);
  float ang = (float)r * (float)(3.14159265358979323846 / 720.0);
  float v = cosf(ang) * 0.07453559924999299f;   // sqrt(2/360)
  if (n == 0) v *= 0.7071067811865476f;
  Dm[idx] = v;
}

// ---------------- Kernel B: M[p][m] = (1/N) sum_n Wlo[p][n] * D[n][m]  (bf16) + row sums ----------------
__global__ __launch_bounds__(384) void k_mmat(const float* __restrict__ Wlo, const float* __restrict__ Dm,
                                              u16* __restrict__ Mbf, float* __restrict__ Srow,
                                              float* __restrict__ Slo){
  int p = blockIdx.x;
  int t = threadIdx.x;
  if (p >= PRED){
    Mbf[(size_t)p*KP + t] = 0;
    if (t == 0){ Srow[p] = 0.f; Slo[p] = 0.f; }
    return;
  }
  __shared__ float Wrow[NIN];
  __shared__ float redM[6], redW[6];
  if (t < NIN) Wrow[t] = Wlo[(size_t)p*NIN + t];
  __syncthreads();
  float acc = 0.f;
  if (t < NIN){
    const float* Dc = Dm + t;
    #pragma unroll 4
    for (int n = 0; n < NIN; n++) acc += Wrow[n] * Dc[(size_t)n*NIN];
    acc *= (1.0f/360.0f);
  }
  Mbf[(size_t)p*KP + t] = (t < NIN) ? to_bf16u(acc) : (u16)0;
  float mv = (t < NIN) ? acc : 0.f;
  float wv = (t < NIN) ? Wrow[t] : 0.f;
  #pragma unroll
  for (int off = 32; off > 0; off >>= 1){
    mv += __shfl_down(mv, off);
    wv += __shfl_down(wv, off);
  }
  int wid = t >> 6, lid = t & 63;
  if (lid == 0){ redM[wid] = mv; redW[wid] = wv; }
  __syncthreads();
  if (t == 0){
    float sm = 0.f, sw = 0.f;
    #pragma unroll
    for (int i = 0; i < 6; i++){ sm += redM[i]; sw += redW[i]; }
    Srow[p] = sm; Slo[p] = sw;
  }
}

// ---------------- Kernel C: pair sums -> bf16 A-matrix, two 192-row halves (R10-verified) ----------------
__global__ __launch_bounds__(256) void k_pre(const float* __restrict__ x, u16* __restrict__ pairB,
                                             float* __restrict__ meanw){
  int b  = blockIdx.y;
  int c0 = blockIdx.x * 64;
  int t  = threadIdx.x;
  int c16  = t & 15;
  int mrow = t >> 4;
  int w    = t >> 6;
  __shared__ u16  pl[192][66];
  __shared__ float red[4][64];
  const float rs2 = 0.7071067811865476f;
  int cb = c0 + c16*4;
  bool full = (cb + 3 < CH);
  const float* xb = x + (size_t)b*SEQ*CH + cb;
  float s0=0.f, s1=0.f, s2=0.f, s3=0.f;
  int rowc = t >> 2;
  int mq0  = t & 3;
  size_t rbase = ((size_t)b*CP + c0 + rowc) * KP;

  #pragma unroll 1
  for (int h = 0; h < 2; h++){
    #pragma unroll 1
    for (int ml = mrow; ml < 192; ml += 16){
      int m = h*192 + ml;
      float p0=0.f, p1=0.f, p2=0.f, p3=0.f;
      if (m < NIN){
        const float* r0 = xb + (size_t)(2*m)*CH;
        float a0,a1,a2,a3, e0,e1,e2,e3;
        if (full){
          f32x4 va = *reinterpret_cast<const f32x4*>(r0);
          f32x2 vb = *reinterpret_cast<const f32x2*>(r0 + CH);
          f32x2 vc = *reinterpret_cast<const f32x2*>(r0 + CH + 2);
          a0=va.x; a1=va.y; a2=va.z; a3=va.w;
          e0=vb.x; e1=vb.y; e2=vc.x; e3=vc.y;
        } else {
          a0 = (cb+0<CH)? r0[0]:0.f; a1 = (cb+1<CH)? r0[1]:0.f;
          a2 = (cb+2<CH)? r0[2]:0.f; a3 = (cb+3<CH)? r0[3]:0.f;
          e0 = (cb+0<CH)? r0[CH+0]:0.f; e1 = (cb+1<CH)? r0[CH+1]:0.f;
          e2 = (cb+2<CH)? r0[CH+2]:0.f; e3 = (cb+3<CH)? r0[CH+3]:0.f;
        }
        p0=a0+e0; p1=a1+e1; p2=a2+e2; p3=a3+e3;
        s0+=p0; s1+=p1; s2+=p2; s3+=p3;
      }
      u32 lo = (u32)to_bf16u(p0*rs2) | ((u32)to_bf16u(p1*rs2) << 16);
      u32 hi = (u32)to_bf16u(p2*rs2) | ((u32)to_bf16u(p3*rs2) << 16);
      *reinterpret_cast<u32*>(&pl[ml][c16*4 + 0]) = lo;
      *reinterpret_cast<u32*>(&pl[ml][c16*4 + 2]) = hi;
    }
    __syncthreads();
    #pragma unroll
    for (int i = 0; i < 6; i++){
      int mg = mq0 + 4*i;
      u16 vals[8];
      #pragma unroll
      for (int j = 0; j < 8; j++) vals[j] = pl[mg*8 + j][rowc];
      uint4 pk;
      pk.x = (u32)vals[0] | ((u32)vals[1] << 16);
      pk.y = (u32)vals[2] | ((u32)vals[3] << 16);
      pk.z = (u32)vals[4] | ((u32)vals[5] << 16);
      pk.w = (u32)vals[6] | ((u32)vals[7] << 16);
      *reinterpret_cast<uint4*>(pairB + rbase + h*192 + (size_t)mg*8) = pk;
    }
    __syncthreads();
  }

  s0 += __shfl_down(s0, 32); s1 += __shfl_down(s1, 32);
  s2 += __shfl_down(s2, 32); s3 += __shfl_down(s3, 32);
  s0 += __shfl_down(s0, 16); s1 += __shfl_down(s1, 16);
  s2 += __shfl_down(s2, 16); s3 += __shfl_down(s3, 16);
  if ((t & 63) < 16){
    f32x4 rv; rv.x=s0; rv.y=s1; rv.z=s2; rv.w=s3;
    *reinterpret_cast<f32x4*>(&red[w][c16*4]) = rv;
  }
  __syncthreads();
  if (t < 64){
    float mean = (red[0][t] + red[1][t] + red[2][t] + red[3][t]) * (1.0f/SEQ);
    meanw[(size_t)b*CP + c0 + t] = mean;
  }
}

// ---------------- Kernel D: barrier-free 1-wave GEMM blocks (64c x 64p per wave) ----------------
// Each block = ONE wave with private double-buffered As/Bs (16 KB). Zero s_barrier:
// all LDS dependences are intra-wave (lgkmcnt, compiler-managed). ~10 independent
// waves/CU overlap each other's stage latency — the TLP the barrier'd versions lacked.
#define GLOAD_LDS16(gp, lp_) __builtin_amdgcn_global_load_lds( \
    (const __attribute__((address_space(1))) u32*)(gp), \
    (__attribute__((address_space(3))) u32*)(lp_), 16, 0, 0)

__global__ __launch_bounds__(64) void k_gemm(const u16* __restrict__ Apack, const u16* __restrict__ Mbf,
                                             const float* __restrict__ Srow, const float* __restrict__ Slo,
                                             const float* __restrict__ meanw,
                                             const float* __restrict__ w1, const float* __restrict__ b1,
                                             const float* __restrict__ w2, const float* __restrict__ b2,
                                             const float* __restrict__ blo,
                                             float* __restrict__ out){
  // XCD swizzle: 10752 = 8 * 1344; 12 consecutive idx share the (b,ct) A-panel.
  int bid = blockIdx.x;
  int idx = (bid & 7) * 1344 + (bid >> 3);
  int pt  = idx % 12;
  int rem = idx / 12;
  int ct  = rem % 14;
  int b   = rem / 14;

  int l = threadIdx.x;            // 0..63, single wave

  __shared__ __align__(16) u16 AsB[2][64*32];   // 8 KB
  __shared__ __align__(16) u16 BsB[2][64*32];   // 8 KB
  float (*wbuf)[68] = reinterpret_cast<float(*)[68]>(&AsB[0][0]);   // epilogue alias [16][68]

  f32x4 acc[4][4] = {};   // c-frag mi x p-frag ni

  const u16* Abase = Apack + ((size_t)b*CP + (size_t)ct*64) * KP;
  const u16* Bbase = Mbf + (size_t)pt*64*KP;
  int row16 = l & 15, kb = l >> 4;
  int rperm = (row16 >> 1) & 3;     // read-side XOR (R4-verified involution)

#define STAGE(bufi, k0) do { \
    _Pragma("unroll") \
    for (int j_ = 0; j_ < 4; j_++){ \
      int r_ = j_*16 + (l >> 2); \
      int q_ = l & 3; \
      int sp_ = (r_ >> 1) & 3; \
      GLOAD_LDS16(Abase + (size_t)r_*KP + (k0) + ((q_^sp_))*8, &AsB[bufi][r_*32 + q_*8]); \
      GLOAD_LDS16(Bbase + (size_t)r_*KP + (k0) + ((q_^sp_))*8, &BsB[bufi][r_*32 + q_*8]); \
    } \
  } while(0)

  STAGE(0, 0);
  for (int ks = 0; ks < 12; ks++){
    int cur = ks & 1;
    if (ks < 11){
      STAGE(cur ^ 1, (ks + 1) * BK);
      asm volatile("s_waitcnt vmcnt(8)" ::: "memory");   // cur's 8 loads landed; next's 8 in flight
    } else {
      asm volatile("s_waitcnt vmcnt(0)" ::: "memory");
    }
    s16x8 af[4], bfr[4];
    #pragma unroll
    for (int mi = 0; mi < 4; mi++)
      af[mi] = *reinterpret_cast<const s16x8*>(&AsB[cur][(mi*16 + row16)*32 + (kb^rperm)*8]);
    #pragma unroll
    for (int ni = 0; ni < 4; ni++)
      bfr[ni] = *reinterpret_cast<const s16x8*>(&BsB[cur][(ni*16 + row16)*32 + (kb^rperm)*8]);
    __builtin_amdgcn_s_setprio(1);
    #pragma unroll
    for (int mi = 0; mi < 4; mi++)
      #pragma unroll
      for (int ni = 0; ni < 4; ni++)
        acc[mi][ni] = __builtin_amdgcn_mfma_f32_16x16x32_bf16(af[mi], bfr[ni], acc[mi][ni], 0, 0, 0);
    __builtin_amdgcn_s_setprio(0);
  }
  asm volatile("s_waitcnt lgkmcnt(0) vmcnt(0)" ::: "memory");   // all LDS reads done before wbuf aliases

  // ---- epilogue: per-wave wbuf [16 p][64 c] -> 256 B-segment stores (R4-verified pattern) ----
  int cq = l & 15, pg = l >> 4;
  int cb4 = ct*64 + cq*4;
  float sc4[4], of4[4], cn4[4], bc4[4];
  #pragma unroll
  for (int j = 0; j < 4; j++){
    int c = cb4 + j;
    bool v = (c < CH);
    float w1v = v ? w1[c] : 0.f, w2v = v ? w2[c] : 0.f;
    float b1v = v ? b1[c] : 0.f, b2v = v ? b2[c] : 0.f;
    float mv  = meanw[(size_t)b*CP + c];     // padded region is 0
    sc4[j] = 1.f + w1v*w2v;
    of4[j] = w1v*b2v + b1v;
    cn4[j] = mv;
    bc4[j] = 1.4142135623730951f * sc4[j] * mv;
  }
  bool cfull = (cb4 + 3 < CH);
  size_t outb = (size_t)b*PRED*CH;

  #pragma unroll
  for (int ni = 0; ni < 4; ni++){
    #pragma unroll
    for (int mi = 0; mi < 4; mi++)
      #pragma unroll
      for (int r = 0; r < 4; r++)
        wbuf[row16][mi*16 + kb*4 + r] = acc[mi][ni][r];
    // intra-wave LDS dep: compiler inserts lgkmcnt before dependent reads
    #pragma unroll
    for (int q = 0; q < 4; q++){
      int pi = q*4 + pg;
      int p = pt*64 + ni*16 + pi;
      if (p < PRED){
        f32x4 g = *reinterpret_cast<const f32x4*>(&wbuf[pi][cq*4]);
        float sp = Srow[p], sl = Slo[p], bl = blo[p];
        f32x4 ov;
        #pragma unroll
        for (int j = 0; j < 4; j++)
          ov[j] = sc4[j]*g[j] + (cn4[j] - bc4[j]*sp + of4[j]*sl + bl);
        float* op = &out[outb + (size_t)p*CH + cb4];
        if (cfull){
          *reinterpret_cast<f32x4*>(op) = ov;
        } else {
          #pragma unroll
          for (int j = 0; j < 4; j++)
            if (cb4 + j < CH) op[j] = ov[j];
        }
      }
    }
    asm volatile("s_waitcnt lgkmcnt(0)" ::: "memory");   // reads done before next ni overwrites wbuf
  }
}

extern "C" void kernel_launch(void* const* d_in, const int* in_sizes, int n_in,
                              void* d_out, int out_size, void* d_ws, size_t ws_size,
                              hipStream_t stream)
{
  const float* x   = (const float*)d_in[0];
  const float* w1  = (const float*)d_in[1];
  const float* b1  = (const float*)d_in[2];
  const float* w2  = (const float*)d_in[3];
  const float* b2  = (const float*)d_in[4];
  const float* Wlo = (const float*)d_in[5];
  const float* blo = (const float*)d_in[6];
  float* out = (float*)d_out;

  char* ws = (char*)d_ws;
  float* Dm    = (float*)(ws);
  u16*   Mbf   = (u16*)(ws + 518400);
  float* Srow  = (float*)(ws + 518400 + 589824);
  float* Slo   = (float*)(ws + 518400 + 589824 + 3072);
  u16*   pairB = (u16*)(ws + 518400 + 589824 + 6144);
  float* meanw = (float*)(ws + 518400 + 589824 + 6144 + 44040192);

  k_dct<<<dim3((NIN*NIN + 255)/256), dim3(256), 0, stream>>>(Dm);
  k_mmat<<<dim3(PP), dim3(384), 0, stream>>>(Wlo, Dm, Mbf, Srow, Slo);
  k_pre<<<dim3(CP/64, NB), dim3(256), 0, stream>>>(x, pairB, meanw);
  k_gemm<<<dim3(NB*14*12), dim3(64), 0, stream>>>(pairB, Mbf, Srow, Slo, meanw,
                                                  w1, b1, w2, b2, blo, out);
}

// Round 18
// 154.478 us; speedup vs baseline: 1.3467x; 1.1825x over previous
//
#include <hip/hip_runtime.h>
#include <hip/hip_bf16.h>
#include <cstdint>

#define SEQ   720
#define PRED  720
#define CH    862
#define NB    64
#define NIN   360   // IN_LEN
#define KP    384   // padded K (12 * 32)
#define CP    896   // padded channels (7 * 128)
#define PP    768   // padded pred (6 * 128)
#define BK    32

typedef __attribute__((ext_vector_type(8))) short s16x8;
typedef __attribute__((ext_vector_type(4))) float f32x4;
typedef __attribute__((ext_vector_type(2))) float f32x2;
typedef unsigned int u32;
typedef unsigned short u16;

__device__ __forceinline__ u16 to_bf16u(float f){
  __hip_bfloat16 h = __float2bfloat16(f);
  return *reinterpret_cast<u16*>(&h);
}

// ---------------- Kernel A: DCT-II ortho matrix D[n][m], n,m in [0,360) ----------------
__global__ __launch_bounds__(256) void k_dct(float* __restrict__ Dm){
  int idx = blockIdx.x*256 + threadIdx.x;
  if (idx >= NIN*NIN) return;
  int n = idx / NIN, m = idx % NIN;
  int r = ((2*m+1)*n) % (4*NIN);
  float ang = (float)r * (float)(3.14159265358979323846 / 720.0);
  float v = cosf(ang) * 0.07453559924999299f;   // sqrt(2/360)
  if (n == 0) v *= 0.7071067811865476f;
  Dm[idx] = v;
}

// ---------------- Kernel B: M[p][m] = (1/N) sum_n Wlo[p][n] * D[n][m]  (bf16) + row sums ----------------
__global__ __launch_bounds__(384) void k_mmat(const float* __restrict__ Wlo, const float* __restrict__ Dm,
                                              u16* __restrict__ Mbf, float* __restrict__ Srow,
                                              float* __restrict__ Slo){
  int p = blockIdx.x;
  int t = threadIdx.x;
  if (p >= PRED){
    Mbf[(size_t)p*KP + t] = 0;
    if (t == 0){ Srow[p] = 0.f; Slo[p] = 0.f; }
    return;
  }
  __shared__ float Wrow[NIN];
  __shared__ float redM[6], redW[6];
  if (t < NIN) Wrow[t] = Wlo[(size_t)p*NIN + t];
  __syncthreads();
  float acc = 0.f;
  if (t < NIN){
    const float* Dc = Dm + t;
    #pragma unroll 4
    for (int n = 0; n < NIN; n++) acc += Wrow[n] * Dc[(size_t)n*NIN];
    acc *= (1.0f/360.0f);
  }
  Mbf[(size_t)p*KP + t] = (t < NIN) ? to_bf16u(acc) : (u16)0;
  float mv = (t < NIN) ? acc : 0.f;
  float wv = (t < NIN) ? Wrow[t] : 0.f;
  #pragma unroll
  for (int off = 32; off > 0; off >>= 1){
    mv += __shfl_down(mv, off);
    wv += __shfl_down(wv, off);
  }
  int wid = t >> 6, lid = t & 63;
  if (lid == 0){ redM[wid] = mv; redW[wid] = wv; }
  __syncthreads();
  if (t == 0){
    float sm = 0.f, sw = 0.f;
    #pragma unroll
    for (int i = 0; i < 6; i++){ sm += redM[i]; sw += redW[i]; }
    Srow[p] = sm; Slo[p] = sw;
  }
}

// ---------------- Kernel C: pair sums -> bf16 A-matrix, two 192-row halves (R10-verified) ----------------
__global__ __launch_bounds__(256) void k_pre(const float* __restrict__ x, u16* __restrict__ pairB,
                                             float* __restrict__ meanw){
  int b  = blockIdx.y;
  int c0 = blockIdx.x * 64;
  int t  = threadIdx.x;
  int c16  = t & 15;
  int mrow = t >> 4;
  int w    = t >> 6;
  __shared__ u16  pl[192][66];     // 25.3 KB -> 6 blocks/CU, all 896 blocks co-resident
  __shared__ float red[4][64];
  const float rs2 = 0.7071067811865476f;
  int cb = c0 + c16*4;
  bool full = (cb + 3 < CH);
  const float* xb = x + (size_t)b*SEQ*CH + cb;
  float s0=0.f, s1=0.f, s2=0.f, s3=0.f;
  int rowc = t >> 2;
  int mq0  = t & 3;
  size_t rbase = ((size_t)b*CP + c0 + rowc) * KP;

  #pragma unroll 1
  for (int h = 0; h < 2; h++){
    #pragma unroll 1
    for (int ml = mrow; ml < 192; ml += 16){
      int m = h*192 + ml;
      float p0=0.f, p1=0.f, p2=0.f, p3=0.f;
      if (m < NIN){
        const float* r0 = xb + (size_t)(2*m)*CH;
        float a0,a1,a2,a3, e0,e1,e2,e3;
        if (full){
          f32x4 va = *reinterpret_cast<const f32x4*>(r0);
          f32x2 vb = *reinterpret_cast<const f32x2*>(r0 + CH);
          f32x2 vc = *reinterpret_cast<const f32x2*>(r0 + CH + 2);
          a0=va.x; a1=va.y; a2=va.z; a3=va.w;
          e0=vb.x; e1=vb.y; e2=vc.x; e3=vc.y;
        } else {
          a0 = (cb+0<CH)? r0[0]:0.f; a1 = (cb+1<CH)? r0[1]:0.f;
          a2 = (cb+2<CH)? r0[2]:0.f; a3 = (cb+3<CH)? r0[3]:0.f;
          e0 = (cb+0<CH)? r0[CH+0]:0.f; e1 = (cb+1<CH)? r0[CH+1]:0.f;
          e2 = (cb+2<CH)? r0[CH+2]:0.f; e3 = (cb+3<CH)? r0[CH+3]:0.f;
        }
        p0=a0+e0; p1=a1+e1; p2=a2+e2; p3=a3+e3;
        s0+=p0; s1+=p1; s2+=p2; s3+=p3;
      }
      u32 lo = (u32)to_bf16u(p0*rs2) | ((u32)to_bf16u(p1*rs2) << 16);
      u32 hi = (u32)to_bf16u(p2*rs2) | ((u32)to_bf16u(p3*rs2) << 16);
      *reinterpret_cast<u32*>(&pl[ml][c16*4 + 0]) = lo;
      *reinterpret_cast<u32*>(&pl[ml][c16*4 + 2]) = hi;
    }
    __syncthreads();
    #pragma unroll
    for (int i = 0; i < 6; i++){
      int mg = mq0 + 4*i;
      u16 vals[8];
      #pragma unroll
      for (int j = 0; j < 8; j++) vals[j] = pl[mg*8 + j][rowc];
      uint4 pk;
      pk.x = (u32)vals[0] | ((u32)vals[1] << 16);
      pk.y = (u32)vals[2] | ((u32)vals[3] << 16);
      pk.z = (u32)vals[4] | ((u32)vals[5] << 16);
      pk.w = (u32)vals[6] | ((u32)vals[7] << 16);
      *reinterpret_cast<uint4*>(pairB + rbase + h*192 + (size_t)mg*8) = pk;
    }
    __syncthreads();
  }

  s0 += __shfl_down(s0, 32); s1 += __shfl_down(s1, 32);
  s2 += __shfl_down(s2, 32); s3 += __shfl_down(s3, 32);
  s0 += __shfl_down(s0, 16); s1 += __shfl_down(s1, 16);
  s2 += __shfl_down(s2, 16); s3 += __shfl_down(s3, 16);
  if ((t & 63) < 16){
    f32x4 rv; rv.x=s0; rv.y=s1; rv.z=s2; rv.w=s3;
    *reinterpret_cast<f32x4*>(&red[w][c16*4]) = rv;
  }
  __syncthreads();
  if (t < 64){
    float mean = (red[0][t] + red[1][t] + red[2][t] + red[3][t]) * (1.0f/SEQ);
    meanw[(size_t)b*CP + c0 + t] = mean;
  }
}

// ---------------- Kernel D: GEMM G = A * M^T (+ fused epilogue) — R8/R10-verified best ----------------
#define GLOAD_LDS16(gp, lp_) __builtin_amdgcn_global_load_lds( \
    (const __attribute__((address_space(1))) u32*)(gp), \
    (__attribute__((address_space(3))) u32*)(lp_), 16, 0, 0)

__global__ __launch_bounds__(256, 4) void k_gemm(const u16* __restrict__ Apack, const u16* __restrict__ Mbf,
                                              const float* __restrict__ Srow, const float* __restrict__ Slo,
                                              const float* __restrict__ meanw,
                                              const float* __restrict__ w1, const float* __restrict__ b1,
                                              const float* __restrict__ w2, const float* __restrict__ b2,
                                              const float* __restrict__ blo,
                                              float* __restrict__ out){
  // XCD-aware bijective swizzle: 2688 = 8 * 336.
  int bid = blockIdx.x;
  int idx = (bid & 7) * 336 + (bid >> 3);
  int pt  = idx % 6;
  int rem = idx / 6;
  int ct  = rem % 7;
  int b   = rem / 7;

  int t  = threadIdx.x;
  int w  = t >> 6, l = t & 63;
  int wr = w >> 1, wc = w & 1;

  // 32 KB union: As[2]+Bs[2] during K-loop; wbuf (16.9 KB) during epilogue.
  __shared__ __align__(16) char smem[32768];
  u16 (*As)[128*BK] = reinterpret_cast<u16(*)[128*BK]>(smem);
  u16 (*Bs)[128*BK] = reinterpret_cast<u16(*)[128*BK]>(smem + 16384);
  float (*wbuf)[16][132] = reinterpret_cast<float(*)[16][132]>(smem);  // [wc][p16][c128+pad]

  f32x4 acc[4][4] = {};

  const u16* Abase = Apack + ((size_t)b*CP + (size_t)ct*128) * KP;
  const u16* Bbase = Mbf + (size_t)pt*128*KP;
  int srow = t >> 2;
  int squad = t & 3;
  int row16 = l & 15, kb = l >> 4;
  int sperm = (srow >> 1) & 3;        // write-side XOR swizzle (global src pre-swizzled)
  int rperm = (row16 >> 1) & 3;       // read-side XOR swizzle (same involution)

#define STAGE(bufi, k0) do { \
    GLOAD_LDS16(Abase + (size_t)(srow)*KP + (k0) + ((squad^sperm))*8,      &As[bufi][(srow)*BK + squad*8]); \
    GLOAD_LDS16(Abase + (size_t)(64 + srow)*KP + (k0) + ((squad^sperm))*8, &As[bufi][(64 + srow)*BK + squad*8]); \
    GLOAD_LDS16(Bbase + (size_t)(srow)*KP + (k0) + ((squad^sperm))*8,      &Bs[bufi][(srow)*BK + squad*8]); \
    GLOAD_LDS16(Bbase + (size_t)(64 + srow)*KP + (k0) + ((squad^sperm))*8, &Bs[bufi][(64 + srow)*BK + squad*8]); \
  } while(0)

  STAGE(0, 0);
  for (int ks = 0; ks < 12; ks++){
    int cur = ks & 1;
    if (ks < 11){
      STAGE(cur ^ 1, (ks + 1) * BK);
      asm volatile("s_waitcnt vmcnt(4)" ::: "memory");
    } else {
      asm volatile("s_waitcnt vmcnt(0)" ::: "memory");
    }
    __builtin_amdgcn_s_barrier();
    s16x8 af[4], bfr[4];
    #pragma unroll
    for (int mi = 0; mi < 4; mi++)
      af[mi] = *reinterpret_cast<const s16x8*>(&As[cur][(wr*64 + mi*16 + row16)*BK + (kb^rperm)*8]);
    #pragma unroll
    for (int ni = 0; ni < 4; ni++)
      bfr[ni] = *reinterpret_cast<const s16x8*>(&Bs[cur][(wc*64 + ni*16 + row16)*BK + (kb^rperm)*8]);
    __builtin_amdgcn_s_setprio(1);
    #pragma unroll
    for (int mi = 0; mi < 4; mi++)
      #pragma unroll
      for (int ni = 0; ni < 4; ni++)
        acc[mi][ni] = __builtin_amdgcn_mfma_f32_16x16x32_bf16(af[mi], bfr[ni], acc[mi][ni], 0, 0, 0);
    __builtin_amdgcn_s_setprio(0);
    __builtin_amdgcn_s_barrier();
  }
  __syncthreads();   // full fence before wbuf aliases As/Bs

  // ---- epilogue: cross-wave wbuf -> 512 B-segment stores ----
  int c32 = t & 31;
  int cb4 = ct*128 + c32*4;
  float sc4[4], of4[4], cn4[4], bc4[4];
  #pragma unroll
  for (int j = 0; j < 4; j++){
    int c = cb4 + j;
    bool v = (c < CH);
    float w1v = v ? w1[c] : 0.f, w2v = v ? w2[c] : 0.f;
    float b1v = v ? b1[c] : 0.f, b2v = v ? b2[c] : 0.f;
    float mv  = v ? meanw[(size_t)b*CP + c] : 0.f;
    sc4[j] = 1.f + w1v*w2v;
    of4[j] = w1v*b2v + b1v;
    cn4[j] = mv;
    bc4[j] = 1.4142135623730951f * sc4[j] * mv;
  }
  bool cfull = (cb4 + 3 < CH);
  size_t outb = (size_t)b*PRED*CH;
  int prow = t >> 5;   // 0..7

  #pragma unroll
  for (int ni = 0; ni < 4; ni++){
    #pragma unroll
    for (int mi = 0; mi < 4; mi++)
      #pragma unroll
      for (int r = 0; r < 4; r++)
        wbuf[wc][row16][wr*64 + mi*16 + kb*4 + r] = acc[mi][ni][r];
    __syncthreads();
    #pragma unroll
    for (int k = 0; k < 4; k++){
      int wcp   = k >> 1;
      int p_loc = (k & 1)*8 + prow;
      int p = pt*128 + wcp*64 + ni*16 + p_loc;
      if (p < PRED){
        f32x4 g = *reinterpret_cast<const f32x4*>(&wbuf[wcp][p_loc][c32*4]);
        float sp = Srow[p], sl = Slo[p], bl = blo[p];
        f32x4 ov;
        #pragma unroll
        for (int j = 0; j < 4; j++)
          ov[j] = sc4[j]*g[j] + (cn4[j] - bc4[j]*sp + of4[j]*sl + bl);
        float* op = &out[outb + (size_t)p*CH + cb4];
        if (cfull){
          *reinterpret_cast<f32x4*>(op) = ov;
        } else {
          #pragma unroll
          for (int j = 0; j < 4; j++)
            if (cb4 + j < CH) op[j] = ov[j];
        }
      }
    }
    __syncthreads();
  }
}

extern "C" void kernel_launch(void* const* d_in, const int* in_sizes, int n_in,
                              void* d_out, int out_size, void* d_ws, size_t ws_size,
                              hipStream_t stream)
{
  const float* x   = (const float*)d_in[0];
  const float* w1  = (const float*)d_in[1];
  const float* b1  = (const float*)d_in[2];
  const float* w2  = (const float*)d_in[3];
  const float* b2  = (const float*)d_in[4];
  const float* Wlo = (const float*)d_in[5];
  const float* blo = (const float*)d_in[6];
  float* out = (float*)d_out;

  char* ws = (char*)d_ws;
  float* Dm    = (float*)(ws);
  u16*   Mbf   = (u16*)(ws + 518400);
  float* Srow  = (float*)(ws + 518400 + 589824);
  float* Slo   = (float*)(ws + 518400 + 589824 + 3072);
  u16*   pairB = (u16*)(ws + 518400 + 589824 + 6144);
  float* meanw = (float*)(ws + 518400 + 589824 + 6144 + 44040192);

  k_dct<<<dim3((NIN*NIN + 255)/256), dim3(256), 0, stream>>>(Dm);
  k_mmat<<<dim3(PP), dim3(384), 0, stream>>>(Wlo, Dm, Mbf, Srow, Slo);
  k_pre<<<dim3(CP/64, NB), dim3(256), 0, stream>>>(x, pairB, meanw);
  k_gemm<<<dim3(6*7*NB), dim3(256), 0, stream>>>(pairB, Mbf, Srow, Slo, meanw,
                                                 w1, b1, w2, b2, blo, out);
}